// Round 21
// baseline (163.244 us; speedup 1.0000x reference)
//
#include <hip/hip_runtime.h>

// GIN forward, bf16 inter-stage tensors:
//   h16a = bf16(x @ W_pre.T + b_pre)
//   h16b = bf16(relu((h16a + seg_sum(h16a[src])) @ W_first.T + b_first))
//   out  = (h16b + seg_sum(h16b[src])) @ W_out.T + b_out   (f32)
// N=100000, E=1600000.
// R19-R21: CHUNK 4096->16384. R18's k_coarse_gemm (38.5us, #1) showed 5.5x
// write amplification in the scatter role (runs of ~10 edges = 40B per bucket
// per chunk -> partial 64B lines). 16k chunks -> runs ~42 edges = 168B -> amp
// ~1.4x. NC 391->98; scan array 4x smaller. Conv and prefix structure
// unchanged (R18 = measured-best composition). (R21 = unchanged resubmit
// after two consecutive infra failures.)

using bf16x8 = __attribute__((ext_vector_type(8))) short;
using f32x4  = __attribute__((ext_vector_type(4))) float;

__device__ inline unsigned short f2bf(float f) {
    unsigned b = __float_as_uint(f);
    return (unsigned short)((b + 0x7FFF + ((b >> 16) & 1)) >> 16);
}
__device__ inline float bf2f_lo(unsigned u) { return __uint_as_float(u << 16); }
__device__ inline float bf2f_hi(unsigned u) { return __uint_as_float(u & 0xFFFF0000u); }
__device__ inline unsigned packbf(float lo, float hi) {
    return (unsigned)f2bf(lo) | ((unsigned)f2bf(hi) << 16);
}
__device__ inline void acc8(float* a, const uint4 u) {
    a[0] += bf2f_lo(u.x); a[1] += bf2f_hi(u.x);
    a[2] += bf2f_lo(u.y); a[3] += bf2f_hi(u.y);
    a[4] += bf2f_lo(u.z); a[5] += bf2f_hi(u.z);
    a[6] += bf2f_lo(u.w); a[7] += bf2f_hi(u.w);
}

constexpr int CHUNK = 16384;  // edges per hist/scatter chunk (write-amp fix)
constexpr int LCAP  = 2048;   // conv LDS edge capacity (mean 1024, +32 sigma)

// ---------------------------------------------------------------------------
// Pre-GEMM tile body (shared by kernels A and B): 64 rows of
// h16a = bf16(x@W_pre.T + b_pre), K=128, MFMA.
// ---------------------------------------------------------------------------
__device__ __forceinline__ void pre_gemm_tile(
    int base, const float* __restrict__ x, const float* __restrict__ Wp,
    const float* __restrict__ bp, unsigned short* __restrict__ h16a, int N)
{
    constexpr int SP = 136;
    __shared__ unsigned short xs[64][SP];
    __shared__ unsigned short ws[64][SP];
    const int tid = threadIdx.x;

    for (int i = tid; i < 64 * 32; i += 256) {     // stage W_pre -> bf16
        const int r = i >> 5, q = i & 31;
        const float4 v = *(const float4*)(Wp + r * 128 + q * 4);
        *(ushort4*)&ws[r][q * 4] =
            make_ushort4(f2bf(v.x), f2bf(v.y), f2bf(v.z), f2bf(v.w));
    }
    for (int i = tid; i < 64 * 32; i += 256) {     // stage x -> bf16
        const int r = i >> 5, q = i & 31;
        int row = base + r; if (row > N - 1) row = N - 1;
        const float4 v = *(const float4*)(x + (size_t)row * 128 + q * 4);
        *(ushort4*)&xs[r][q * 4] =
            make_ushort4(f2bf(v.x), f2bf(v.y), f2bf(v.z), f2bf(v.w));
    }
    __syncthreads();

    const int w = tid >> 6, l = tid & 63, lr = l & 15, lg = l >> 4;
    f32x4 acc[4];
#pragma unroll
    for (int nb = 0; nb < 4; ++nb) {
        const float bv = bp[nb * 16 + lr];
        acc[nb] = (f32x4){bv, bv, bv, bv};
    }
#pragma unroll
    for (int kb = 0; kb < 4; ++kb) {
        const bf16x8 a = *(const bf16x8*)&xs[w * 16 + lr][kb * 32 + lg * 8];
#pragma unroll
        for (int nb = 0; nb < 4; ++nb) {
            const bf16x8 b = *(const bf16x8*)&ws[nb * 16 + lr][kb * 32 + lg * 8];
            acc[nb] = __builtin_amdgcn_mfma_f32_16x16x32_bf16(a, b, acc[nb], 0, 0, 0);
        }
    }
#pragma unroll
    for (int nb = 0; nb < 4; ++nb) {
#pragma unroll
        for (int r = 0; r < 4; ++r) {
            const int row = base + w * 16 + lg * 4 + r;
            if (row < N)
                h16a[(size_t)row * 64 + nb * 16 + lr] = f2bf(acc[nb][r]);
        }
    }
}

// ---------------------------------------------------------------------------
// Standalone per-chunk coarse (256-node bucket) histogram.
// ---------------------------------------------------------------------------
__global__ __launch_bounds__(256) void p_hist(
    const int* __restrict__ dst, int* __restrict__ ccounts,
    int E, int NBKC, int NC)
{
    __shared__ int cnt[512];
    const int tid = threadIdx.x;
    const int c = blockIdx.x;
    for (int b = tid; b < NBKC; b += 256) cnt[b] = 0;
    __syncthreads();
    const int beg = c * CHUNK, end = min(beg + CHUNK, E);
    for (int e = beg + tid; e < end; e += 256)
        atomicAdd(&cnt[dst[e] >> 8], 1);
    __syncthreads();
    for (int b = tid; b < NBKC; b += 256) ccounts[b * NC + c] = cnt[b];
}

// ---------------------------------------------------------------------------
// Scan chain over ccounts (coarse-bucket-major).
// ---------------------------------------------------------------------------
__global__ __launch_bounds__(512) void k_blocksum(
    const int* __restrict__ in, int* __restrict__ partial, int n)
{
    __shared__ int s[512];
    const int i = blockIdx.x * 512 + threadIdx.x;
    s[threadIdx.x] = (i < n) ? in[i] : 0;
    __syncthreads();
    for (int off = 256; off > 0; off >>= 1) {
        if (threadIdx.x < off) s[threadIdx.x] += s[threadIdx.x + off];
        __syncthreads();
    }
    if (threadIdx.x == 0) partial[blockIdx.x] = s[0];
}

__global__ __launch_bounds__(1024) void k_scanpartial1024(
    int* __restrict__ partial, int nblk)
{
    __shared__ int s[1024];
    const int t = threadIdx.x;
    s[t] = (t < nblk) ? partial[t] : 0;
    __syncthreads();
    for (int off = 1; off < 1024; off <<= 1) {
        const int v = (t >= off) ? s[t - off] : 0;
        __syncthreads();
        s[t] += v;
        __syncthreads();
    }
    if (t < nblk) partial[t] = (t == 0) ? 0 : s[t - 1];
}

__global__ __launch_bounds__(512) void k_exscan(
    int* __restrict__ data, const int* __restrict__ partial, int n)
{
    __shared__ int s[512];
    const int i = blockIdx.x * 512 + threadIdx.x;
    const int t = threadIdx.x;
    const int v = (i < n) ? data[i] : 0;
    s[t] = v;
    __syncthreads();
    for (int off = 1; off < 512; off <<= 1) {
        const int u = (t >= off) ? s[t - off] : 0;
        __syncthreads();
        s[t] += u;
        __syncthreads();
    }
    if (i < n) data[i] = partial[blockIdx.x] + s[t] - v;   // exclusive
}

// ---------------------------------------------------------------------------
// Kernel A: blocks [0,NC) = coarse scatter; [NC, NC+GA) = pre-GEMM tiles.
// ---------------------------------------------------------------------------
__global__ __launch_bounds__(256) void k_coarse_gemm(
    const int* __restrict__ src, const int* __restrict__ dst,
    const int* __restrict__ ccounts, unsigned* __restrict__ slots,
    const float* __restrict__ x, const float* __restrict__ Wp,
    const float* __restrict__ bp, unsigned short* __restrict__ h16a,
    int N, int E, int NBKC, int NC)
{
    if ((int)blockIdx.x < NC) {                    // ---- coarse scatter ----
        __shared__ int cur[512];
        const int c = blockIdx.x;
        for (int b = threadIdx.x; b < NBKC; b += 256) cur[b] = ccounts[b * NC + c];
        __syncthreads();
        const int beg = c * CHUNK;
        const int end = min(beg + CHUNK, E);
        for (int e = beg + threadIdx.x; e < end; e += 256) {
            const int d = dst[e];
            const int pos = atomicAdd(&cur[d >> 8], 1);
            slots[pos] = ((unsigned)(d & 255) << 24) | (unsigned)src[e];
        }
        return;
    }
    pre_gemm_tile((blockIdx.x - NC) * 64, x, Wp, bp, h16a, N);
}

// ---------------------------------------------------------------------------
// Kernel B: blocks [0,NBKC) = fine node-sort; rest = pre-GEMM tiles [GA,GB).
// ---------------------------------------------------------------------------
__global__ __launch_bounds__(256) void k_fine_gemm(
    const unsigned* __restrict__ slots, const int* __restrict__ ccounts,
    unsigned* __restrict__ slots2, int* __restrict__ noffs,
    const float* __restrict__ x, const float* __restrict__ Wp,
    const float* __restrict__ bp, unsigned short* __restrict__ h16a,
    int GA, int N, int E, int NBKC, int NC)
{
    if ((int)blockIdx.x < NBKC) {                  // ---- fine node sort ----
        __shared__ int hist[256], psum[256], cur[256];
        const int cb  = blockIdx.x;
        const int tid = threadIdx.x;
        const int cbase = ccounts[cb * NC];
        const int cend  = (cb + 1 < NBKC) ? ccounts[(cb + 1) * NC] : E;

        hist[tid] = 0;
        __syncthreads();
        for (int i = cbase + tid; i < cend; i += 256)
            atomicAdd(&hist[slots[i] >> 24], 1);
        __syncthreads();

        psum[tid] = hist[tid];
        __syncthreads();
        for (int off = 1; off < 256; off <<= 1) {
            const int v = (tid >= off) ? psum[tid - off] : 0;
            __syncthreads();
            psum[tid] += v;
            __syncthreads();
        }
        const int o = cbase + psum[tid] - hist[tid];   // exclusive
        cur[tid] = o;
        const int gnode = cb * 256 + tid;
        if (gnode < N) noffs[gnode] = o;
        if (cb == NBKC - 1 && tid == 0) noffs[N] = cend;
        __syncthreads();

        for (int i = cbase + tid; i < cend; i += 256) {
            const unsigned p = slots[i];
            const int pos = atomicAdd(&cur[p >> 24], 1);
            slots2[pos] = p & 0x00FFFFFFu;             // plain src id
        }
        return;
    }
    pre_gemm_tile((GA + blockIdx.x - NBKC) * 64, x, Wp, bp, h16a, N);
}

// ---------------------------------------------------------------------------
// Fused conv (R12-best): 256-thread block = 64 nodes. W staged to LDS during
// setup; lsl LDS id staging; per-node register walk (8 lanes/node, 8-deep)
// with work-stealing; MFMA K=64, 4 waves x 16 rows.
// ---------------------------------------------------------------------------
template <int RELU, int WF32>
__global__ __launch_bounds__(256) void conv_fused(
    const unsigned short* __restrict__ hin, const unsigned* __restrict__ slots2,
    const int* __restrict__ noffs, const float* __restrict__ W,
    const float* __restrict__ bias, float* __restrict__ outf,
    unsigned short* __restrict__ out16, int N)
{
    constexpr int SPW = 72;
    __shared__ unsigned short ws[64][SPW];         // 9216 B
    __shared__ unsigned short xs[64][SPW];         // 9216 B
    __shared__ unsigned lsl[LCAP];                 // 8192 B src ids
    __shared__ int loffs[65];
    __shared__ int steal;

    const int tid  = threadIdx.x;
    const int base = blockIdx.x * 64;

    for (int i = tid; i < 64 * 16; i += 256) {     // stage W -> bf16
        const int r = i >> 4, q = i & 15;
        const float4 v = *(const float4*)(W + r * 64 + q * 4);
        *(ushort4*)&ws[r][q * 4] =
            make_ushort4(f2bf(v.x), f2bf(v.y), f2bf(v.z), f2bf(v.w));
    }
    if (tid <= 64) loffs[tid] = noffs[min(base + tid, N)];
    if (tid == 0) steal = 0;
    const int beg  = noffs[base];
    const int cend = noffs[min(base + 64, N)];
    const int cnt  = cend - beg;
    for (int i = tid; i < min(cnt, LCAP); i += 256) lsl[i] = slots2[beg + i];
    __syncthreads();

    // ---- per-node walk, work-stealing over 64 nodes ----
    const int l = tid & 63;
    const int leader = l & ~7;
    const int c = (l & 7) * 8;
    while (true) {
        int n = 0;
        if ((l & 7) == 0) n = atomicAdd(&steal, 1);
        n = __shfl(n, leader);
        if (n >= 64) break;
        const int node = base + n;
        float a[8] = {0.f, 0.f, 0.f, 0.f, 0.f, 0.f, 0.f, 0.f};
        if (node < N) {
            acc8(a, *(const uint4*)(hin + (size_t)node * 64 + c));  // self
            int j = loffs[n] - beg;
            const int hi = loffs[n + 1] - beg;
            const int hiL = min(hi, LCAP);
            for (; j + 8 <= hiL; j += 8) {         // 8 rows in flight
                const unsigned s0 = lsl[j],     s1 = lsl[j + 1];
                const unsigned s2 = lsl[j + 2], s3 = lsl[j + 3];
                const unsigned s4 = lsl[j + 4], s5 = lsl[j + 5];
                const unsigned s6 = lsl[j + 6], s7 = lsl[j + 7];
                const uint4 u0 = *(const uint4*)(hin + (size_t)s0 * 64 + c);
                const uint4 u1 = *(const uint4*)(hin + (size_t)s1 * 64 + c);
                const uint4 u2 = *(const uint4*)(hin + (size_t)s2 * 64 + c);
                const uint4 u3 = *(const uint4*)(hin + (size_t)s3 * 64 + c);
                const uint4 u4 = *(const uint4*)(hin + (size_t)s4 * 64 + c);
                const uint4 u5 = *(const uint4*)(hin + (size_t)s5 * 64 + c);
                const uint4 u6 = *(const uint4*)(hin + (size_t)s6 * 64 + c);
                const uint4 u7 = *(const uint4*)(hin + (size_t)s7 * 64 + c);
                acc8(a, u0); acc8(a, u1); acc8(a, u2); acc8(a, u3);
                acc8(a, u4); acc8(a, u5); acc8(a, u6); acc8(a, u7);
            }
            for (; j + 4 <= hiL; j += 4) {
                const unsigned s0 = lsl[j],     s1 = lsl[j + 1];
                const unsigned s2 = lsl[j + 2], s3 = lsl[j + 3];
                const uint4 u0 = *(const uint4*)(hin + (size_t)s0 * 64 + c);
                const uint4 u1 = *(const uint4*)(hin + (size_t)s1 * 64 + c);
                const uint4 u2 = *(const uint4*)(hin + (size_t)s2 * 64 + c);
                const uint4 u3 = *(const uint4*)(hin + (size_t)s3 * 64 + c);
                acc8(a, u0); acc8(a, u1); acc8(a, u2); acc8(a, u3);
            }
            for (; j < hiL; ++j)
                acc8(a, *(const uint4*)(hin + (size_t)lsl[j] * 64 + c));
            for (; j < hi; ++j) {                  // LDS-overflow tail (rare)
                const unsigned s = slots2[beg + j];
                acc8(a, *(const uint4*)(hin + (size_t)s * 64 + c));
            }
        }
        *(uint4*)&xs[n][c] =
            make_uint4(packbf(a[0], a[1]), packbf(a[2], a[3]),
                       packbf(a[4], a[5]), packbf(a[6], a[7]));
    }
    __syncthreads();

    // ---- MFMA, K=64: 4 waves x 16 rows ----
    const int w = tid >> 6, lr = l & 15, lg = l >> 4;
    f32x4 acc[4];
#pragma unroll
    for (int nb = 0; nb < 4; ++nb) {
        const float bv = bias[nb * 16 + lr];
        acc[nb] = (f32x4){bv, bv, bv, bv};
    }
#pragma unroll
    for (int kb = 0; kb < 2; ++kb) {
        const bf16x8 a = *(const bf16x8*)&xs[w * 16 + lr][kb * 32 + lg * 8];
#pragma unroll
        for (int nb = 0; nb < 4; ++nb) {
            const bf16x8 b = *(const bf16x8*)&ws[nb * 16 + lr][kb * 32 + lg * 8];
            acc[nb] = __builtin_amdgcn_mfma_f32_16x16x32_bf16(a, b, acc[nb], 0, 0, 0);
        }
    }
#pragma unroll
    for (int nb = 0; nb < 4; ++nb) {
#pragma unroll
        for (int r = 0; r < 4; ++r) {
            const int row = base + w * 16 + lg * 4 + r;
            if (row < N) {
                float v = acc[nb][r];
                if (RELU) v = fmaxf(v, 0.f);
                if (WF32) outf[(size_t)row * 64 + nb * 16 + lr] = v;
                else      out16[(size_t)row * 64 + nb * 16 + lr] = f2bf(v);
            }
        }
    }
}

extern "C" void kernel_launch(void* const* d_in, const int* in_sizes, int n_in,
                              void* d_out, int out_size, void* d_ws, size_t ws_size,
                              hipStream_t stream)
{
    const float* x       = (const float*)d_in[0];
    const int*   ei      = (const int*)  d_in[1];
    const float* W_pre   = (const float*)d_in[2];
    const float* b_pre   = (const float*)d_in[3];
    const float* W_first = (const float*)d_in[4];
    const float* b_first = (const float*)d_in[5];
    const float* W_out   = (const float*)d_in[6];
    const float* b_out   = (const float*)d_in[7];

    const int N = in_sizes[0] / 128;
    const int E = in_sizes[1] / 2;
    const int* src = ei;
    const int* dst = ei + E;

    const int NBKC  = (N + 255) / 256;            // 391 coarse buckets
    const int NC    = (E + CHUNK - 1) / CHUNK;    // 98 chunks
    const int nscan = NBKC * NC;                  // 38,318
    const int nsblk = (nscan + 511) / 512;        // 75 <= 1024
    const int GB    = (N + 63) / 64;              // 1563 pre-GEMM tiles
    const int GA    = GB / 2;                     // 781 in kernel A
    const int CB    = (N + 63) / 64;              // 1563 conv blocks

    // Workspace (~38.9 MB):
    unsigned short* h16a   = (unsigned short*)d_ws;              // [N*64]
    unsigned short* h16b   = h16a + (size_t)N * 64;              // [N*64]
    unsigned*       slots  = (unsigned*)(h16b + (size_t)N * 64); // [E]
    unsigned*       slots2 = slots + E;                          // [E]
    int*            ccounts= (int*)(slots2 + E);                 // [nscan]
    int*            partial= ccounts + nscan;                    // [<=1024]
    int*            noffs  = partial + 1024;                     // [N+1]

    float* out = (float*)d_out;

    // 1. coarse histogram (standalone: scan doesn't wait on GEMM)
    p_hist<<<NC, 256, 0, stream>>>(dst, ccounts, E, NBKC, NC);

    // 2. scan chain over ccounts
    k_blocksum<<<nsblk, 512, 0, stream>>>(ccounts, partial, nscan);
    k_scanpartial1024<<<1, 1024, 0, stream>>>(partial, nsblk);
    k_exscan<<<nsblk, 512, 0, stream>>>(ccounts, partial, nscan);

    // 3. coarse scatter || pre-GEMM tiles [0,GA)
    k_coarse_gemm<<<NC + GA, 256, 0, stream>>>(
        src, dst, ccounts, slots, x, W_pre, b_pre, h16a, N, E, NBKC, NC);

    // 4. fine node-sort || pre-GEMM tiles [GA,GB)
    k_fine_gemm<<<NBKC + (GB - GA), 256, 0, stream>>>(
        slots, ccounts, slots2, noffs, x, W_pre, b_pre, h16a,
        GA, N, E, NBKC, NC);

    // 5. conv1 fused -> h16b (bf16, relu)
    conv_fused<1, 0><<<CB, 256, 0, stream>>>(
        h16a, slots2, noffs, W_first, b_first, nullptr, h16b, N);

    // 6. conv2 fused -> d_out (f32)
    conv_fused<0, 1><<<CB, 256, 0, stream>>>(
        h16b, slots2, noffs, W_out, b_out, out, nullptr, N);
}

// Round 22
// 133.516 us; speedup vs baseline: 1.2226x; 1.2226x over previous
//
#include <hip/hip_runtime.h>

// GIN forward, bf16 inter-stage tensors:
//   h16a = bf16(x @ W_pre.T + b_pre)
//   h16b = bf16(relu((h16a + seg_sum(h16a[src])) @ W_first.T + b_first))
//   out  = (h16b + seg_sum(h16b[src])) @ W_out.T + b_out   (f32)
// N=100000, E=1600000.
// R22: CHUNK=8192 (middle of the scatter tradeoff: blocks x run-length is
// fixed at E/NBKC~4092; R18's 4096 was write-amp-bound 5.5x, R21's 16384 was
// tail-bound at 98 blocks/10% occ). 196 blocks, runs ~21 edges (~2.5x amp).
// Scatter loop unrolled 4-wide for independent atomic->store chains.
// Rest identical to R18 (measured best 130.7us).

using bf16x8 = __attribute__((ext_vector_type(8))) short;
using f32x4  = __attribute__((ext_vector_type(4))) float;

__device__ inline unsigned short f2bf(float f) {
    unsigned b = __float_as_uint(f);
    return (unsigned short)((b + 0x7FFF + ((b >> 16) & 1)) >> 16);
}
__device__ inline float bf2f_lo(unsigned u) { return __uint_as_float(u << 16); }
__device__ inline float bf2f_hi(unsigned u) { return __uint_as_float(u & 0xFFFF0000u); }
__device__ inline unsigned packbf(float lo, float hi) {
    return (unsigned)f2bf(lo) | ((unsigned)f2bf(hi) << 16);
}
__device__ inline void acc8(float* a, const uint4 u) {
    a[0] += bf2f_lo(u.x); a[1] += bf2f_hi(u.x);
    a[2] += bf2f_lo(u.y); a[3] += bf2f_hi(u.y);
    a[4] += bf2f_lo(u.z); a[5] += bf2f_hi(u.z);
    a[6] += bf2f_lo(u.w); a[7] += bf2f_hi(u.w);
}

constexpr int CHUNK = 8192;   // edges per hist/scatter chunk
constexpr int LCAP  = 2048;   // conv LDS edge capacity (mean 1024, +32 sigma)

// ---------------------------------------------------------------------------
// Pre-GEMM tile body (shared by kernels A and B): 64 rows of
// h16a = bf16(x@W_pre.T + b_pre), K=128, MFMA.
// ---------------------------------------------------------------------------
__device__ __forceinline__ void pre_gemm_tile(
    int base, const float* __restrict__ x, const float* __restrict__ Wp,
    const float* __restrict__ bp, unsigned short* __restrict__ h16a, int N)
{
    constexpr int SP = 136;
    __shared__ unsigned short xs[64][SP];
    __shared__ unsigned short ws[64][SP];
    const int tid = threadIdx.x;

    for (int i = tid; i < 64 * 32; i += 256) {     // stage W_pre -> bf16
        const int r = i >> 5, q = i & 31;
        const float4 v = *(const float4*)(Wp + r * 128 + q * 4);
        *(ushort4*)&ws[r][q * 4] =
            make_ushort4(f2bf(v.x), f2bf(v.y), f2bf(v.z), f2bf(v.w));
    }
    for (int i = tid; i < 64 * 32; i += 256) {     // stage x -> bf16
        const int r = i >> 5, q = i & 31;
        int row = base + r; if (row > N - 1) row = N - 1;
        const float4 v = *(const float4*)(x + (size_t)row * 128 + q * 4);
        *(ushort4*)&xs[r][q * 4] =
            make_ushort4(f2bf(v.x), f2bf(v.y), f2bf(v.z), f2bf(v.w));
    }
    __syncthreads();

    const int w = tid >> 6, l = tid & 63, lr = l & 15, lg = l >> 4;
    f32x4 acc[4];
#pragma unroll
    for (int nb = 0; nb < 4; ++nb) {
        const float bv = bp[nb * 16 + lr];
        acc[nb] = (f32x4){bv, bv, bv, bv};
    }
#pragma unroll
    for (int kb = 0; kb < 4; ++kb) {
        const bf16x8 a = *(const bf16x8*)&xs[w * 16 + lr][kb * 32 + lg * 8];
#pragma unroll
        for (int nb = 0; nb < 4; ++nb) {
            const bf16x8 b = *(const bf16x8*)&ws[nb * 16 + lr][kb * 32 + lg * 8];
            acc[nb] = __builtin_amdgcn_mfma_f32_16x16x32_bf16(a, b, acc[nb], 0, 0, 0);
        }
    }
#pragma unroll
    for (int nb = 0; nb < 4; ++nb) {
#pragma unroll
        for (int r = 0; r < 4; ++r) {
            const int row = base + w * 16 + lg * 4 + r;
            if (row < N)
                h16a[(size_t)row * 64 + nb * 16 + lr] = f2bf(acc[nb][r]);
        }
    }
}

// ---------------------------------------------------------------------------
// Standalone per-chunk coarse (256-node bucket) histogram.
// ---------------------------------------------------------------------------
__global__ __launch_bounds__(256) void p_hist(
    const int* __restrict__ dst, int* __restrict__ ccounts,
    int E, int NBKC, int NC)
{
    __shared__ int cnt[512];
    const int tid = threadIdx.x;
    const int c = blockIdx.x;
    for (int b = tid; b < NBKC; b += 256) cnt[b] = 0;
    __syncthreads();
    const int beg = c * CHUNK, end = min(beg + CHUNK, E);
    for (int e = beg + tid; e < end; e += 256)
        atomicAdd(&cnt[dst[e] >> 8], 1);
    __syncthreads();
    for (int b = tid; b < NBKC; b += 256) ccounts[b * NC + c] = cnt[b];
}

// ---------------------------------------------------------------------------
// Scan chain over ccounts (coarse-bucket-major).
// ---------------------------------------------------------------------------
__global__ __launch_bounds__(512) void k_blocksum(
    const int* __restrict__ in, int* __restrict__ partial, int n)
{
    __shared__ int s[512];
    const int i = blockIdx.x * 512 + threadIdx.x;
    s[threadIdx.x] = (i < n) ? in[i] : 0;
    __syncthreads();
    for (int off = 256; off > 0; off >>= 1) {
        if (threadIdx.x < off) s[threadIdx.x] += s[threadIdx.x + off];
        __syncthreads();
    }
    if (threadIdx.x == 0) partial[blockIdx.x] = s[0];
}

__global__ __launch_bounds__(1024) void k_scanpartial1024(
    int* __restrict__ partial, int nblk)
{
    __shared__ int s[1024];
    const int t = threadIdx.x;
    s[t] = (t < nblk) ? partial[t] : 0;
    __syncthreads();
    for (int off = 1; off < 1024; off <<= 1) {
        const int v = (t >= off) ? s[t - off] : 0;
        __syncthreads();
        s[t] += v;
        __syncthreads();
    }
    if (t < nblk) partial[t] = (t == 0) ? 0 : s[t - 1];
}

__global__ __launch_bounds__(512) void k_exscan(
    int* __restrict__ data, const int* __restrict__ partial, int n)
{
    __shared__ int s[512];
    const int i = blockIdx.x * 512 + threadIdx.x;
    const int t = threadIdx.x;
    const int v = (i < n) ? data[i] : 0;
    s[t] = v;
    __syncthreads();
    for (int off = 1; off < 512; off <<= 1) {
        const int u = (t >= off) ? s[t - off] : 0;
        __syncthreads();
        s[t] += u;
        __syncthreads();
    }
    if (i < n) data[i] = partial[blockIdx.x] + s[t] - v;   // exclusive
}

// ---------------------------------------------------------------------------
// Kernel A: blocks [0,NC) = coarse scatter (4-wide unrolled); rest = GEMM.
// ---------------------------------------------------------------------------
__global__ __launch_bounds__(256) void k_coarse_gemm(
    const int* __restrict__ src, const int* __restrict__ dst,
    const int* __restrict__ ccounts, unsigned* __restrict__ slots,
    const float* __restrict__ x, const float* __restrict__ Wp,
    const float* __restrict__ bp, unsigned short* __restrict__ h16a,
    int N, int E, int NBKC, int NC)
{
    if ((int)blockIdx.x < NC) {                    // ---- coarse scatter ----
        __shared__ int cur[512];
        const int c = blockIdx.x;
        for (int b = threadIdx.x; b < NBKC; b += 256) cur[b] = ccounts[b * NC + c];
        __syncthreads();
        const int beg = c * CHUNK;
        const int end = min(beg + CHUNK, E);
        for (int e0 = beg + threadIdx.x * 4; e0 < end; e0 += 1024) {
#pragma unroll
            for (int k = 0; k < 4; ++k) {
                const int e = e0 + k;
                if (e < end) {
                    const int d = dst[e];
                    const int pos = atomicAdd(&cur[d >> 8], 1);
                    slots[pos] = ((unsigned)(d & 255) << 24) | (unsigned)src[e];
                }
            }
        }
        return;
    }
    pre_gemm_tile((blockIdx.x - NC) * 64, x, Wp, bp, h16a, N);
}

// ---------------------------------------------------------------------------
// Kernel B: blocks [0,NBKC) = fine node-sort; rest = pre-GEMM tiles [GA,GB).
// ---------------------------------------------------------------------------
__global__ __launch_bounds__(256) void k_fine_gemm(
    const unsigned* __restrict__ slots, const int* __restrict__ ccounts,
    unsigned* __restrict__ slots2, int* __restrict__ noffs,
    const float* __restrict__ x, const float* __restrict__ Wp,
    const float* __restrict__ bp, unsigned short* __restrict__ h16a,
    int GA, int N, int E, int NBKC, int NC)
{
    if ((int)blockIdx.x < NBKC) {                  // ---- fine node sort ----
        __shared__ int hist[256], psum[256], cur[256];
        const int cb  = blockIdx.x;
        const int tid = threadIdx.x;
        const int cbase = ccounts[cb * NC];
        const int cend  = (cb + 1 < NBKC) ? ccounts[(cb + 1) * NC] : E;

        hist[tid] = 0;
        __syncthreads();
        for (int i = cbase + tid; i < cend; i += 256)
            atomicAdd(&hist[slots[i] >> 24], 1);
        __syncthreads();

        psum[tid] = hist[tid];
        __syncthreads();
        for (int off = 1; off < 256; off <<= 1) {
            const int v = (tid >= off) ? psum[tid - off] : 0;
            __syncthreads();
            psum[tid] += v;
            __syncthreads();
        }
        const int o = cbase + psum[tid] - hist[tid];   // exclusive
        cur[tid] = o;
        const int gnode = cb * 256 + tid;
        if (gnode < N) noffs[gnode] = o;
        if (cb == NBKC - 1 && tid == 0) noffs[N] = cend;
        __syncthreads();

        for (int i = cbase + tid; i < cend; i += 256) {
            const unsigned p = slots[i];
            const int pos = atomicAdd(&cur[p >> 24], 1);
            slots2[pos] = p & 0x00FFFFFFu;             // plain src id
        }
        return;
    }
    pre_gemm_tile((GA + blockIdx.x - NBKC) * 64, x, Wp, bp, h16a, N);
}

// ---------------------------------------------------------------------------
// Fused conv (R12-best): 256-thread block = 64 nodes. W staged to LDS during
// setup; lsl LDS id staging; per-node register walk (8 lanes/node, 8-deep)
// with work-stealing; MFMA K=64, 4 waves x 16 rows.
// ---------------------------------------------------------------------------
template <int RELU, int WF32>
__global__ __launch_bounds__(256) void conv_fused(
    const unsigned short* __restrict__ hin, const unsigned* __restrict__ slots2,
    const int* __restrict__ noffs, const float* __restrict__ W,
    const float* __restrict__ bias, float* __restrict__ outf,
    unsigned short* __restrict__ out16, int N)
{
    constexpr int SPW = 72;
    __shared__ unsigned short ws[64][SPW];         // 9216 B
    __shared__ unsigned short xs[64][SPW];         // 9216 B
    __shared__ unsigned lsl[LCAP];                 // 8192 B src ids
    __shared__ int loffs[65];
    __shared__ int steal;

    const int tid  = threadIdx.x;
    const int base = blockIdx.x * 64;

    for (int i = tid; i < 64 * 16; i += 256) {     // stage W -> bf16
        const int r = i >> 4, q = i & 15;
        const float4 v = *(const float4*)(W + r * 64 + q * 4);
        *(ushort4*)&ws[r][q * 4] =
            make_ushort4(f2bf(v.x), f2bf(v.y), f2bf(v.z), f2bf(v.w));
    }
    if (tid <= 64) loffs[tid] = noffs[min(base + tid, N)];
    if (tid == 0) steal = 0;
    const int beg  = noffs[base];
    const int cend = noffs[min(base + 64, N)];
    const int cnt  = cend - beg;
    for (int i = tid; i < min(cnt, LCAP); i += 256) lsl[i] = slots2[beg + i];
    __syncthreads();

    // ---- per-node walk, work-stealing over 64 nodes ----
    const int l = tid & 63;
    const int leader = l & ~7;
    const int c = (l & 7) * 8;
    while (true) {
        int n = 0;
        if ((l & 7) == 0) n = atomicAdd(&steal, 1);
        n = __shfl(n, leader);
        if (n >= 64) break;
        const int node = base + n;
        float a[8] = {0.f, 0.f, 0.f, 0.f, 0.f, 0.f, 0.f, 0.f};
        if (node < N) {
            acc8(a, *(const uint4*)(hin + (size_t)node * 64 + c));  // self
            int j = loffs[n] - beg;
            const int hi = loffs[n + 1] - beg;
            const int hiL = min(hi, LCAP);
            for (; j + 8 <= hiL; j += 8) {         // 8 rows in flight
                const unsigned s0 = lsl[j],     s1 = lsl[j + 1];
                const unsigned s2 = lsl[j + 2], s3 = lsl[j + 3];
                const unsigned s4 = lsl[j + 4], s5 = lsl[j + 5];
                const unsigned s6 = lsl[j + 6], s7 = lsl[j + 7];
                const uint4 u0 = *(const uint4*)(hin + (size_t)s0 * 64 + c);
                const uint4 u1 = *(const uint4*)(hin + (size_t)s1 * 64 + c);
                const uint4 u2 = *(const uint4*)(hin + (size_t)s2 * 64 + c);
                const uint4 u3 = *(const uint4*)(hin + (size_t)s3 * 64 + c);
                const uint4 u4 = *(const uint4*)(hin + (size_t)s4 * 64 + c);
                const uint4 u5 = *(const uint4*)(hin + (size_t)s5 * 64 + c);
                const uint4 u6 = *(const uint4*)(hin + (size_t)s6 * 64 + c);
                const uint4 u7 = *(const uint4*)(hin + (size_t)s7 * 64 + c);
                acc8(a, u0); acc8(a, u1); acc8(a, u2); acc8(a, u3);
                acc8(a, u4); acc8(a, u5); acc8(a, u6); acc8(a, u7);
            }
            for (; j + 4 <= hiL; j += 4) {
                const unsigned s0 = lsl[j],     s1 = lsl[j + 1];
                const unsigned s2 = lsl[j + 2], s3 = lsl[j + 3];
                const uint4 u0 = *(const uint4*)(hin + (size_t)s0 * 64 + c);
                const uint4 u1 = *(const uint4*)(hin + (size_t)s1 * 64 + c);
                const uint4 u2 = *(const uint4*)(hin + (size_t)s2 * 64 + c);
                const uint4 u3 = *(const uint4*)(hin + (size_t)s3 * 64 + c);
                acc8(a, u0); acc8(a, u1); acc8(a, u2); acc8(a, u3);
            }
            for (; j < hiL; ++j)
                acc8(a, *(const uint4*)(hin + (size_t)lsl[j] * 64 + c));
            for (; j < hi; ++j) {                  // LDS-overflow tail (rare)
                const unsigned s = slots2[beg + j];
                acc8(a, *(const uint4*)(hin + (size_t)s * 64 + c));
            }
        }
        *(uint4*)&xs[n][c] =
            make_uint4(packbf(a[0], a[1]), packbf(a[2], a[3]),
                       packbf(a[4], a[5]), packbf(a[6], a[7]));
    }
    __syncthreads();

    // ---- MFMA, K=64: 4 waves x 16 rows ----
    const int w = tid >> 6, lr = l & 15, lg = l >> 4;
    f32x4 acc[4];
#pragma unroll
    for (int nb = 0; nb < 4; ++nb) {
        const float bv = bias[nb * 16 + lr];
        acc[nb] = (f32x4){bv, bv, bv, bv};
    }
#pragma unroll
    for (int kb = 0; kb < 2; ++kb) {
        const bf16x8 a = *(const bf16x8*)&xs[w * 16 + lr][kb * 32 + lg * 8];
#pragma unroll
        for (int nb = 0; nb < 4; ++nb) {
            const bf16x8 b = *(const bf16x8*)&ws[nb * 16 + lr][kb * 32 + lg * 8];
            acc[nb] = __builtin_amdgcn_mfma_f32_16x16x32_bf16(a, b, acc[nb], 0, 0, 0);
        }
    }
#pragma unroll
    for (int nb = 0; nb < 4; ++nb) {
#pragma unroll
        for (int r = 0; r < 4; ++r) {
            const int row = base + w * 16 + lg * 4 + r;
            if (row < N) {
                float v = acc[nb][r];
                if (RELU) v = fmaxf(v, 0.f);
                if (WF32) outf[(size_t)row * 64 + nb * 16 + lr] = v;
                else      out16[(size_t)row * 64 + nb * 16 + lr] = f2bf(v);
            }
        }
    }
}

extern "C" void kernel_launch(void* const* d_in, const int* in_sizes, int n_in,
                              void* d_out, int out_size, void* d_ws, size_t ws_size,
                              hipStream_t stream)
{
    const float* x       = (const float*)d_in[0];
    const int*   ei      = (const int*)  d_in[1];
    const float* W_pre   = (const float*)d_in[2];
    const float* b_pre   = (const float*)d_in[3];
    const float* W_first = (const float*)d_in[4];
    const float* b_first = (const float*)d_in[5];
    const float* W_out   = (const float*)d_in[6];
    const float* b_out   = (const float*)d_in[7];

    const int N = in_sizes[0] / 128;
    const int E = in_sizes[1] / 2;
    const int* src = ei;
    const int* dst = ei + E;

    const int NBKC  = (N + 255) / 256;            // 391 coarse buckets
    const int NC    = (E + CHUNK - 1) / CHUNK;    // 196 chunks
    const int nscan = NBKC * NC;                  // 76,636
    const int nsblk = (nscan + 511) / 512;        // 150 <= 1024
    const int GB    = (N + 63) / 64;              // 1563 pre-GEMM tiles
    const int GA    = GB / 2;                     // 781 in kernel A
    const int CB    = (N + 63) / 64;              // 1563 conv blocks

    // Workspace (~39.2 MB):
    unsigned short* h16a   = (unsigned short*)d_ws;              // [N*64]
    unsigned short* h16b   = h16a + (size_t)N * 64;              // [N*64]
    unsigned*       slots  = (unsigned*)(h16b + (size_t)N * 64); // [E]
    unsigned*       slots2 = slots + E;                          // [E]
    int*            ccounts= (int*)(slots2 + E);                 // [nscan]
    int*            partial= ccounts + nscan;                    // [<=1024]
    int*            noffs  = partial + 1024;                     // [N+1]

    float* out = (float*)d_out;

    // 1. coarse histogram (standalone: scan doesn't wait on GEMM)
    p_hist<<<NC, 256, 0, stream>>>(dst, ccounts, E, NBKC, NC);

    // 2. scan chain over ccounts
    k_blocksum<<<nsblk, 512, 0, stream>>>(ccounts, partial, nscan);
    k_scanpartial1024<<<1, 1024, 0, stream>>>(partial, nsblk);
    k_exscan<<<nsblk, 512, 0, stream>>>(ccounts, partial, nscan);

    // 3. coarse scatter || pre-GEMM tiles [0,GA)
    k_coarse_gemm<<<NC + GA, 256, 0, stream>>>(
        src, dst, ccounts, slots, x, W_pre, b_pre, h16a, N, E, NBKC, NC);

    // 4. fine node-sort || pre-GEMM tiles [GA,GB)
    k_fine_gemm<<<NBKC + (GB - GA), 256, 0, stream>>>(
        slots, ccounts, slots2, noffs, x, W_pre, b_pre, h16a,
        GA, N, E, NBKC, NC);

    // 5. conv1 fused -> h16b (bf16, relu)
    conv_fused<1, 0><<<CB, 256, 0, stream>>>(
        h16a, slots2, noffs, W_first, b_first, nullptr, h16b, N);

    // 6. conv2 fused -> d_out (f32)
    conv_fused<0, 1><<<CB, 256, 0, stream>>>(
        h16b, slots2, noffs, W_out, b_out, out, nullptr, N);
}

// Round 23
// 129.880 us; speedup vs baseline: 1.2569x; 1.0280x over previous
//
#include <hip/hip_runtime.h>

// GIN forward, bf16 inter-stage tensors:
//   h16a = bf16(x @ W_pre.T + b_pre)
//   h16b = bf16(relu((h16a + seg_sum(h16a[src])) @ W_first.T + b_first))
//   out  = (h16b + seg_sum(h16b[src])) @ W_out.T + b_out   (f32)
// N=100000, E=1600000.
// R23: revert to R18 exactly (measured best, 130.7us). CHUNK sweep complete:
// 4096=130.7 / 8192=133.5 / 16384=163.2 -> 4096 optimal. Convs pinned at the
// random-row cross-XCD gather ceiling (5 failed restructure attempts);
// prefix fully overlapped. This locks in the best-known configuration.

using bf16x8 = __attribute__((ext_vector_type(8))) short;
using f32x4  = __attribute__((ext_vector_type(4))) float;

__device__ inline unsigned short f2bf(float f) {
    unsigned b = __float_as_uint(f);
    return (unsigned short)((b + 0x7FFF + ((b >> 16) & 1)) >> 16);
}
__device__ inline float bf2f_lo(unsigned u) { return __uint_as_float(u << 16); }
__device__ inline float bf2f_hi(unsigned u) { return __uint_as_float(u & 0xFFFF0000u); }
__device__ inline unsigned packbf(float lo, float hi) {
    return (unsigned)f2bf(lo) | ((unsigned)f2bf(hi) << 16);
}
__device__ inline void acc8(float* a, const uint4 u) {
    a[0] += bf2f_lo(u.x); a[1] += bf2f_hi(u.x);
    a[2] += bf2f_lo(u.y); a[3] += bf2f_hi(u.y);
    a[4] += bf2f_lo(u.z); a[5] += bf2f_hi(u.z);
    a[6] += bf2f_lo(u.w); a[7] += bf2f_hi(u.w);
}

constexpr int CHUNK = 4096;   // edges per hist/scatter chunk (R18 optimum)
constexpr int LCAP  = 2048;   // conv LDS edge capacity (mean 1024, +32 sigma)

// ---------------------------------------------------------------------------
// Pre-GEMM tile body (shared by kernels A and B): 64 rows of
// h16a = bf16(x@W_pre.T + b_pre), K=128, MFMA.
// ---------------------------------------------------------------------------
__device__ __forceinline__ void pre_gemm_tile(
    int base, const float* __restrict__ x, const float* __restrict__ Wp,
    const float* __restrict__ bp, unsigned short* __restrict__ h16a, int N)
{
    constexpr int SP = 136;
    __shared__ unsigned short xs[64][SP];
    __shared__ unsigned short ws[64][SP];
    const int tid = threadIdx.x;

    for (int i = tid; i < 64 * 32; i += 256) {     // stage W_pre -> bf16
        const int r = i >> 5, q = i & 31;
        const float4 v = *(const float4*)(Wp + r * 128 + q * 4);
        *(ushort4*)&ws[r][q * 4] =
            make_ushort4(f2bf(v.x), f2bf(v.y), f2bf(v.z), f2bf(v.w));
    }
    for (int i = tid; i < 64 * 32; i += 256) {     // stage x -> bf16
        const int r = i >> 5, q = i & 31;
        int row = base + r; if (row > N - 1) row = N - 1;
        const float4 v = *(const float4*)(x + (size_t)row * 128 + q * 4);
        *(ushort4*)&xs[r][q * 4] =
            make_ushort4(f2bf(v.x), f2bf(v.y), f2bf(v.z), f2bf(v.w));
    }
    __syncthreads();

    const int w = tid >> 6, l = tid & 63, lr = l & 15, lg = l >> 4;
    f32x4 acc[4];
#pragma unroll
    for (int nb = 0; nb < 4; ++nb) {
        const float bv = bp[nb * 16 + lr];
        acc[nb] = (f32x4){bv, bv, bv, bv};
    }
#pragma unroll
    for (int kb = 0; kb < 4; ++kb) {
        const bf16x8 a = *(const bf16x8*)&xs[w * 16 + lr][kb * 32 + lg * 8];
#pragma unroll
        for (int nb = 0; nb < 4; ++nb) {
            const bf16x8 b = *(const bf16x8*)&ws[nb * 16 + lr][kb * 32 + lg * 8];
            acc[nb] = __builtin_amdgcn_mfma_f32_16x16x32_bf16(a, b, acc[nb], 0, 0, 0);
        }
    }
#pragma unroll
    for (int nb = 0; nb < 4; ++nb) {
#pragma unroll
        for (int r = 0; r < 4; ++r) {
            const int row = base + w * 16 + lg * 4 + r;
            if (row < N)
                h16a[(size_t)row * 64 + nb * 16 + lr] = f2bf(acc[nb][r]);
        }
    }
}

// ---------------------------------------------------------------------------
// Standalone per-chunk coarse (256-node bucket) histogram.
// ---------------------------------------------------------------------------
__global__ __launch_bounds__(256) void p_hist(
    const int* __restrict__ dst, int* __restrict__ ccounts,
    int E, int NBKC, int NC)
{
    __shared__ int cnt[512];
    const int tid = threadIdx.x;
    const int c = blockIdx.x;
    for (int b = tid; b < NBKC; b += 256) cnt[b] = 0;
    __syncthreads();
    const int beg = c * CHUNK, end = min(beg + CHUNK, E);
    for (int e = beg + tid; e < end; e += 256)
        atomicAdd(&cnt[dst[e] >> 8], 1);
    __syncthreads();
    for (int b = tid; b < NBKC; b += 256) ccounts[b * NC + c] = cnt[b];
}

// ---------------------------------------------------------------------------
// Scan chain over ccounts (coarse-bucket-major).
// ---------------------------------------------------------------------------
__global__ __launch_bounds__(512) void k_blocksum(
    const int* __restrict__ in, int* __restrict__ partial, int n)
{
    __shared__ int s[512];
    const int i = blockIdx.x * 512 + threadIdx.x;
    s[threadIdx.x] = (i < n) ? in[i] : 0;
    __syncthreads();
    for (int off = 256; off > 0; off >>= 1) {
        if (threadIdx.x < off) s[threadIdx.x] += s[threadIdx.x + off];
        __syncthreads();
    }
    if (threadIdx.x == 0) partial[blockIdx.x] = s[0];
}

__global__ __launch_bounds__(1024) void k_scanpartial1024(
    int* __restrict__ partial, int nblk)
{
    __shared__ int s[1024];
    const int t = threadIdx.x;
    s[t] = (t < nblk) ? partial[t] : 0;
    __syncthreads();
    for (int off = 1; off < 1024; off <<= 1) {
        const int v = (t >= off) ? s[t - off] : 0;
        __syncthreads();
        s[t] += v;
        __syncthreads();
    }
    if (t < nblk) partial[t] = (t == 0) ? 0 : s[t - 1];
}

__global__ __launch_bounds__(512) void k_exscan(
    int* __restrict__ data, const int* __restrict__ partial, int n)
{
    __shared__ int s[512];
    const int i = blockIdx.x * 512 + threadIdx.x;
    const int t = threadIdx.x;
    const int v = (i < n) ? data[i] : 0;
    s[t] = v;
    __syncthreads();
    for (int off = 1; off < 512; off <<= 1) {
        const int u = (t >= off) ? s[t - off] : 0;
        __syncthreads();
        s[t] += u;
        __syncthreads();
    }
    if (i < n) data[i] = partial[blockIdx.x] + s[t] - v;   // exclusive
}

// ---------------------------------------------------------------------------
// Kernel A: blocks [0,NC) = coarse scatter; [NC, NC+GA) = pre-GEMM tiles.
// ---------------------------------------------------------------------------
__global__ __launch_bounds__(256) void k_coarse_gemm(
    const int* __restrict__ src, const int* __restrict__ dst,
    const int* __restrict__ ccounts, unsigned* __restrict__ slots,
    const float* __restrict__ x, const float* __restrict__ Wp,
    const float* __restrict__ bp, unsigned short* __restrict__ h16a,
    int N, int E, int NBKC, int NC)
{
    if ((int)blockIdx.x < NC) {                    // ---- coarse scatter ----
        __shared__ int cur[512];
        const int c = blockIdx.x;
        for (int b = threadIdx.x; b < NBKC; b += 256) cur[b] = ccounts[b * NC + c];
        __syncthreads();
        const int beg = c * CHUNK;
        const int end = min(beg + CHUNK, E);
        for (int e = beg + threadIdx.x; e < end; e += 256) {
            const int d = dst[e];
            const int pos = atomicAdd(&cur[d >> 8], 1);
            slots[pos] = ((unsigned)(d & 255) << 24) | (unsigned)src[e];
        }
        return;
    }
    pre_gemm_tile((blockIdx.x - NC) * 64, x, Wp, bp, h16a, N);
}

// ---------------------------------------------------------------------------
// Kernel B: blocks [0,NBKC) = fine node-sort; rest = pre-GEMM tiles [GA,GB).
// ---------------------------------------------------------------------------
__global__ __launch_bounds__(256) void k_fine_gemm(
    const unsigned* __restrict__ slots, const int* __restrict__ ccounts,
    unsigned* __restrict__ slots2, int* __restrict__ noffs,
    const float* __restrict__ x, const float* __restrict__ Wp,
    const float* __restrict__ bp, unsigned short* __restrict__ h16a,
    int GA, int N, int E, int NBKC, int NC)
{
    if ((int)blockIdx.x < NBKC) {                  // ---- fine node sort ----
        __shared__ int hist[256], psum[256], cur[256];
        const int cb  = blockIdx.x;
        const int tid = threadIdx.x;
        const int cbase = ccounts[cb * NC];
        const int cend  = (cb + 1 < NBKC) ? ccounts[(cb + 1) * NC] : E;

        hist[tid] = 0;
        __syncthreads();
        for (int i = cbase + tid; i < cend; i += 256)
            atomicAdd(&hist[slots[i] >> 24], 1);
        __syncthreads();

        psum[tid] = hist[tid];
        __syncthreads();
        for (int off = 1; off < 256; off <<= 1) {
            const int v = (tid >= off) ? psum[tid - off] : 0;
            __syncthreads();
            psum[tid] += v;
            __syncthreads();
        }
        const int o = cbase + psum[tid] - hist[tid];   // exclusive
        cur[tid] = o;
        const int gnode = cb * 256 + tid;
        if (gnode < N) noffs[gnode] = o;
        if (cb == NBKC - 1 && tid == 0) noffs[N] = cend;
        __syncthreads();

        for (int i = cbase + tid; i < cend; i += 256) {
            const unsigned p = slots[i];
            const int pos = atomicAdd(&cur[p >> 24], 1);
            slots2[pos] = p & 0x00FFFFFFu;             // plain src id
        }
        return;
    }
    pre_gemm_tile((GA + blockIdx.x - NBKC) * 64, x, Wp, bp, h16a, N);
}

// ---------------------------------------------------------------------------
// Fused conv (R12-best): 256-thread block = 64 nodes. W staged to LDS during
// setup; lsl LDS id staging; per-node register walk (8 lanes/node, 8-deep)
// with work-stealing; MFMA K=64, 4 waves x 16 rows.
// ---------------------------------------------------------------------------
template <int RELU, int WF32>
__global__ __launch_bounds__(256) void conv_fused(
    const unsigned short* __restrict__ hin, const unsigned* __restrict__ slots2,
    const int* __restrict__ noffs, const float* __restrict__ W,
    const float* __restrict__ bias, float* __restrict__ outf,
    unsigned short* __restrict__ out16, int N)
{
    constexpr int SPW = 72;
    __shared__ unsigned short ws[64][SPW];         // 9216 B
    __shared__ unsigned short xs[64][SPW];         // 9216 B
    __shared__ unsigned lsl[LCAP];                 // 8192 B src ids
    __shared__ int loffs[65];
    __shared__ int steal;

    const int tid  = threadIdx.x;
    const int base = blockIdx.x * 64;

    for (int i = tid; i < 64 * 16; i += 256) {     // stage W -> bf16
        const int r = i >> 4, q = i & 15;
        const float4 v = *(const float4*)(W + r * 64 + q * 4);
        *(ushort4*)&ws[r][q * 4] =
            make_ushort4(f2bf(v.x), f2bf(v.y), f2bf(v.z), f2bf(v.w));
    }
    if (tid <= 64) loffs[tid] = noffs[min(base + tid, N)];
    if (tid == 0) steal = 0;
    const int beg  = noffs[base];
    const int cend = noffs[min(base + 64, N)];
    const int cnt  = cend - beg;
    for (int i = tid; i < min(cnt, LCAP); i += 256) lsl[i] = slots2[beg + i];
    __syncthreads();

    // ---- per-node walk, work-stealing over 64 nodes ----
    const int l = tid & 63;
    const int leader = l & ~7;
    const int c = (l & 7) * 8;
    while (true) {
        int n = 0;
        if ((l & 7) == 0) n = atomicAdd(&steal, 1);
        n = __shfl(n, leader);
        if (n >= 64) break;
        const int node = base + n;
        float a[8] = {0.f, 0.f, 0.f, 0.f, 0.f, 0.f, 0.f, 0.f};
        if (node < N) {
            acc8(a, *(const uint4*)(hin + (size_t)node * 64 + c));  // self
            int j = loffs[n] - beg;
            const int hi = loffs[n + 1] - beg;
            const int hiL = min(hi, LCAP);
            for (; j + 8 <= hiL; j += 8) {         // 8 rows in flight
                const unsigned s0 = lsl[j],     s1 = lsl[j + 1];
                const unsigned s2 = lsl[j + 2], s3 = lsl[j + 3];
                const unsigned s4 = lsl[j + 4], s5 = lsl[j + 5];
                const unsigned s6 = lsl[j + 6], s7 = lsl[j + 7];
                const uint4 u0 = *(const uint4*)(hin + (size_t)s0 * 64 + c);
                const uint4 u1 = *(const uint4*)(hin + (size_t)s1 * 64 + c);
                const uint4 u2 = *(const uint4*)(hin + (size_t)s2 * 64 + c);
                const uint4 u3 = *(const uint4*)(hin + (size_t)s3 * 64 + c);
                const uint4 u4 = *(const uint4*)(hin + (size_t)s4 * 64 + c);
                const uint4 u5 = *(const uint4*)(hin + (size_t)s5 * 64 + c);
                const uint4 u6 = *(const uint4*)(hin + (size_t)s6 * 64 + c);
                const uint4 u7 = *(const uint4*)(hin + (size_t)s7 * 64 + c);
                acc8(a, u0); acc8(a, u1); acc8(a, u2); acc8(a, u3);
                acc8(a, u4); acc8(a, u5); acc8(a, u6); acc8(a, u7);
            }
            for (; j + 4 <= hiL; j += 4) {
                const unsigned s0 = lsl[j],     s1 = lsl[j + 1];
                const unsigned s2 = lsl[j + 2], s3 = lsl[j + 3];
                const uint4 u0 = *(const uint4*)(hin + (size_t)s0 * 64 + c);
                const uint4 u1 = *(const uint4*)(hin + (size_t)s1 * 64 + c);
                const uint4 u2 = *(const uint4*)(hin + (size_t)s2 * 64 + c);
                const uint4 u3 = *(const uint4*)(hin + (size_t)s3 * 64 + c);
                acc8(a, u0); acc8(a, u1); acc8(a, u2); acc8(a, u3);
            }
            for (; j < hiL; ++j)
                acc8(a, *(const uint4*)(hin + (size_t)lsl[j] * 64 + c));
            for (; j < hi; ++j) {                  // LDS-overflow tail (rare)
                const unsigned s = slots2[beg + j];
                acc8(a, *(const uint4*)(hin + (size_t)s * 64 + c));
            }
        }
        *(uint4*)&xs[n][c] =
            make_uint4(packbf(a[0], a[1]), packbf(a[2], a[3]),
                       packbf(a[4], a[5]), packbf(a[6], a[7]));
    }
    __syncthreads();

    // ---- MFMA, K=64: 4 waves x 16 rows ----
    const int w = tid >> 6, lr = l & 15, lg = l >> 4;
    f32x4 acc[4];
#pragma unroll
    for (int nb = 0; nb < 4; ++nb) {
        const float bv = bias[nb * 16 + lr];
        acc[nb] = (f32x4){bv, bv, bv, bv};
    }
#pragma unroll
    for (int kb = 0; kb < 2; ++kb) {
        const bf16x8 a = *(const bf16x8*)&xs[w * 16 + lr][kb * 32 + lg * 8];
#pragma unroll
        for (int nb = 0; nb < 4; ++nb) {
            const bf16x8 b = *(const bf16x8*)&ws[nb * 16 + lr][kb * 32 + lg * 8];
            acc[nb] = __builtin_amdgcn_mfma_f32_16x16x32_bf16(a, b, acc[nb], 0, 0, 0);
        }
    }
#pragma unroll
    for (int nb = 0; nb < 4; ++nb) {
#pragma unroll
        for (int r = 0; r < 4; ++r) {
            const int row = base + w * 16 + lg * 4 + r;
            if (row < N) {
                float v = acc[nb][r];
                if (RELU) v = fmaxf(v, 0.f);
                if (WF32) outf[(size_t)row * 64 + nb * 16 + lr] = v;
                else      out16[(size_t)row * 64 + nb * 16 + lr] = f2bf(v);
            }
        }
    }
}

extern "C" void kernel_launch(void* const* d_in, const int* in_sizes, int n_in,
                              void* d_out, int out_size, void* d_ws, size_t ws_size,
                              hipStream_t stream)
{
    const float* x       = (const float*)d_in[0];
    const int*   ei      = (const int*)  d_in[1];
    const float* W_pre   = (const float*)d_in[2];
    const float* b_pre   = (const float*)d_in[3];
    const float* W_first = (const float*)d_in[4];
    const float* b_first = (const float*)d_in[5];
    const float* W_out   = (const float*)d_in[6];
    const float* b_out   = (const float*)d_in[7];

    const int N = in_sizes[0] / 128;
    const int E = in_sizes[1] / 2;
    const int* src = ei;
    const int* dst = ei + E;

    const int NBKC  = (N + 255) / 256;            // 391 coarse buckets
    const int NC    = (E + CHUNK - 1) / CHUNK;    // 391 chunks
    const int nscan = NBKC * NC;                  // 152,881
    const int nsblk = (nscan + 511) / 512;        // 299 <= 1024
    const int GB    = (N + 63) / 64;              // 1563 pre-GEMM tiles
    const int GA    = GB / 2;                     // 781 in kernel A
    const int CB    = (N + 63) / 64;              // 1563 conv blocks

    // Workspace (~39.4 MB):
    unsigned short* h16a   = (unsigned short*)d_ws;              // [N*64]
    unsigned short* h16b   = h16a + (size_t)N * 64;              // [N*64]
    unsigned*       slots  = (unsigned*)(h16b + (size_t)N * 64); // [E]
    unsigned*       slots2 = slots + E;                          // [E]
    int*            ccounts= (int*)(slots2 + E);                 // [nscan]
    int*            partial= ccounts + nscan;                    // [<=1024]
    int*            noffs  = partial + 1024;                     // [N+1]

    float* out = (float*)d_out;

    // 1. coarse histogram (standalone: scan doesn't wait on GEMM)
    p_hist<<<NC, 256, 0, stream>>>(dst, ccounts, E, NBKC, NC);

    // 2. scan chain over ccounts
    k_blocksum<<<nsblk, 512, 0, stream>>>(ccounts, partial, nscan);
    k_scanpartial1024<<<1, 1024, 0, stream>>>(partial, nsblk);
    k_exscan<<<nsblk, 512, 0, stream>>>(ccounts, partial, nscan);

    // 3. coarse scatter || pre-GEMM tiles [0,GA)
    k_coarse_gemm<<<NC + GA, 256, 0, stream>>>(
        src, dst, ccounts, slots, x, W_pre, b_pre, h16a, N, E, NBKC, NC);

    // 4. fine node-sort || pre-GEMM tiles [GA,GB)
    k_fine_gemm<<<NBKC + (GB - GA), 256, 0, stream>>>(
        slots, ccounts, slots2, noffs, x, W_pre, b_pre, h16a,
        GA, N, E, NBKC, NC);

    // 5. conv1 fused -> h16b (bf16, relu)
    conv_fused<1, 0><<<CB, 256, 0, stream>>>(
        h16a, slots2, noffs, W_first, b_first, nullptr, h16b, N);

    // 6. conv2 fused -> d_out (f32)
    conv_fused<0, 1><<<CB, 256, 0, stream>>>(
        h16b, slots2, noffs, W_out, b_out, out, nullptr, N);
}